// Round 6
// baseline (270.821 us; speedup 1.0000x reference)
//
#include <hip/hip_runtime.h>

typedef __attribute__((ext_vector_type(8))) short bf16x8;
typedef __attribute__((ext_vector_type(4))) float f32x4;
typedef unsigned short ushort_t;

#define N 4096

__device__ __forceinline__ unsigned short f2bf_rne(float f) {
  unsigned int u = __float_as_uint(f);
  u += 0x7fffu + ((u >> 16) & 1u);
  return (unsigned short)(u >> 16);
}

// One block per row (8192 rows: Z then Y). fp32 row norm + bf16 copy.
__global__ __launch_bounds__(256) void prep_kernel(
    const float* __restrict__ Z, const float* __restrict__ Y,
    ushort_t* __restrict__ Zb, ushort_t* __restrict__ Yb,
    float* __restrict__ norms) {
  const int r = blockIdx.x;
  const bool isZ = (r < N);
  const int rr = isZ ? r : r - N;
  const float* __restrict__ src = (isZ ? Z : Y) + (size_t)rr * N;
  ushort_t* __restrict__ dst = (isZ ? Zb : Yb) + (size_t)rr * N;
  const int t = threadIdx.x;

  float s = 0.f;
#pragma unroll
  for (int j = 0; j < 4; ++j) {
    const float4 v = ((const float4*)src)[j * 256 + t];
    s += v.x * v.x + v.y * v.y + v.z * v.z + v.w * v.w;
    short4 o;
    o.x = (short)f2bf_rne(v.x);
    o.y = (short)f2bf_rne(v.y);
    o.z = (short)f2bf_rne(v.z);
    o.w = (short)f2bf_rne(v.w);
    ((short4*)dst)[j * 256 + t] = o;
  }
#pragma unroll
  for (int off = 32; off > 0; off >>= 1) s += __shfl_down(s, off, 64);
  __shared__ float red[4];
  const int lane = t & 63, w = t >> 6;
  if (lane == 0) red[w] = s;
  __syncthreads();
  if (t == 0) norms[r] = sqrtf(red[0] + red[1] + red[2] + red[3]);
}

// ---- 256x256 tile, BK=64, 4 waves each owning 128x128, 2-deep dbuf ------
// LDS per buf (64KB): A0 @0 (rows 0-127), A1 @16384, B0 @32768, B1 @49152.
// buf1 = +65536. Row = 128B, 8 slots of 16B, swizzle slot ^= (row&7).
// Per K-tile: 4 quadrants of 32 MFMA; quadrant q issues reads for q+1;
// all 16 stage-GLDs for T+1 in Q1; single vmcnt(0)+barrier before Q4.
__global__ __launch_bounds__(256, 1) void gemm_kernel(
    const ushort_t* __restrict__ A,   // Zb [N][N]
    const ushort_t* __restrict__ B,   // Yb [N][N]
    const float* __restrict__ norms,  // [2N]: nx then ny
    float* __restrict__ out) {
  __shared__ __align__(16) char smem[131072];

  const int bid = blockIdx.x;                 // 256 blocks; bijective swizzle
  const int swz = (bid & 7) * 32 + (bid >> 3);
  const int tile_row = swz >> 4;
  const int tile_col = swz & 15;

  const int tid = threadIdx.x;
  const int l = tid & 63;
  const int w = tid >> 6;     // 0..3
  const int wr = w >> 1;      // M half (128 rows)
  const int wc = w & 1;       // N half (128 cols)
  const int li = l & 15;
  const int sl = l >> 4;

  // staging: chunk ch = q*256 + tid writes LDS [region + ch*16, +16) linear;
  // LDS(row,slot) holds global(row, slot ^ (row&7)).
  const ushort_t* pgA[4];
  const ushort_t* pgB[4];
#pragma unroll
  for (int q = 0; q < 4; ++q) {
    const int ch = q * 256 + tid;
    const int row = ch >> 3;              // 0..127 within region
    const int scol = ((ch & 7) ^ (row & 7)) * 8;
    pgA[q] = A + (size_t)(tile_row * 256 + row) * N + scol;
    pgB[q] = B + (size_t)(tile_col * 256 + row) * N + scol;
  }

#define GLD(SRC, DST)                                              \
  __builtin_amdgcn_global_load_lds(                                \
      (__attribute__((address_space(1))) void*)(SRC),              \
      (__attribute__((address_space(3))) void*)(DST), 16, 0, 0)

  // stage full K-tile T1 (A0,A1,B0,B1) into buffer at byte base BUFB
#define STAGE_ALL(T1, BUFB) { _Pragma("unroll")                               \
    for (int q = 0; q < 4; ++q) {                                             \
      const size_t ko = (size_t)(T1) * 64;                                    \
      GLD(pgA[q] + ko,                  smem + (BUFB) +         q*4096 + w*1024); \
      GLD(pgA[q] + (size_t)128*N + ko,  smem + (BUFB) + 16384 + q*4096 + w*1024); \
      GLD(pgB[q] + ko,                  smem + (BUFB) + 32768 + q*4096 + w*1024); \
      GLD(pgB[q] + (size_t)128*N + ko,  smem + (BUFB) + 49152 + q*4096 + w*1024); \
    } }

  // fragment bases
  const int rbA = wr * 16384 + li * 128;            // A region + row byte
  const int rbB = 32768 + wc * 16384 + li * 128;    // B region + row byte
  const int sb0 = ((sl) ^ (li & 7)) * 16;           // k-half 0 slot
  const int sb1 = ((sl + 4) ^ (li & 7)) * 16;       // k-half 1 slot

  // DST[mm][kh]; MH selects m-range 0..3 / 4..7 (8192B = 4 rows of 16)
#define RD_A(DST, BUFB, MH) { _Pragma("unroll")                               \
    for (int mm = 0; mm < 4; ++mm) {                                          \
      DST[mm][0] = *(const bf16x8*)(smem + (BUFB) + rbA + (MH)*8192 + mm*2048 + sb0); \
      DST[mm][1] = *(const bf16x8*)(smem + (BUFB) + rbA + (MH)*8192 + mm*2048 + sb1); } }
#define RD_B(DST, BUFB, NH) { _Pragma("unroll")                               \
    for (int nn = 0; nn < 4; ++nn) {                                          \
      DST[nn][0] = *(const bf16x8*)(smem + (BUFB) + rbB + (NH)*8192 + nn*2048 + sb0); \
      DST[nn][1] = *(const bf16x8*)(smem + (BUFB) + rbB + (NH)*8192 + nn*2048 + sb1); } }

  f32x4 acc[8][8];
#pragma unroll
  for (int m = 0; m < 8; ++m)
#pragma unroll
    for (int n = 0; n < 8; ++n) acc[m][n] = (f32x4){0.f, 0.f, 0.f, 0.f};

#define MF(AF, BF, QM, QN) { _Pragma("unroll")                                \
    for (int kh = 0; kh < 2; ++kh)                                            \
    _Pragma("unroll") for (int mm = 0; mm < 4; ++mm)                          \
    _Pragma("unroll") for (int nn = 0; nn < 4; ++nn)                          \
      acc[(QM)*4+mm][(QN)*4+nn] = __builtin_amdgcn_mfma_f32_16x16x32_bf16(    \
          AF[mm][kh], BF[nn][kh], acc[(QM)*4+mm][(QN)*4+nn], 0, 0, 0); }

#define SB  __builtin_amdgcn_sched_barrier(0);
#define VM0 asm volatile("s_waitcnt vmcnt(0)" ::: "memory");
#define BARC { __builtin_amdgcn_s_barrier(); __builtin_amdgcn_sched_barrier(0); }

  // frag slots: even tile: ml@aX mh@aY; odd tile: ml@aY mh@aX; B: nl@bX nh@bY
  bf16x8 aX[4][2], aY[4][2], bX[4][2], bY[4][2];

  // Quadrant order: Q1(ml,nl) Q2(mh,nl) Q3(mh,nh) [gate] Q4(ml,nh).
  // Q1 stages T+1 (16 GLD) and reads mh(T); Q2 reads nh(T);
  // Q4 prefetches ml(T+1)->AMH-slot, nl(T+1)->bX from the new buffer.
#define QT(T_, BC, BN_, AML, AMH, DOSTAGE, DOGATE, DOPREF) {                  \
    if (DOSTAGE) STAGE_ALL((T_) + 1, BN_);                                    \
    RD_A(AMH, BC, 1);                                                         \
    SB;                                                                       \
    MF(AML, bX, 0, 0);                                                        \
    SB;                                                                       \
    RD_B(bY, BC, 1);                                                          \
    SB;                                                                       \
    MF(AMH, bX, 1, 0);                                                        \
    SB;                                                                       \
    MF(AMH, bY, 1, 1);                                                        \
    SB;                                                                       \
    if (DOGATE) { VM0; BARC; }                                                \
    if (DOPREF) { RD_A(AMH, BN_, 0); RD_B(bX, BN_, 0); }                      \
    SB;                                                                       \
    MF(AML, bY, 0, 1);                                                        \
    SB; }

  // prologue: stage tile 0, gate, prime ml(0)/nl(0)
  STAGE_ALL(0, 0);
  VM0; BARC;
  RD_A(aX, 0, 0);
  RD_B(bX, 0, 0);

#pragma unroll 1
  for (int p = 0; p < 31; ++p) {
    QT(2 * p,     0,     65536, aX, aY, 1, 1, 1);
    QT(2 * p + 1, 65536, 0,     aY, aX, 1, 1, 1);
  }
  QT(62, 0,     65536, aX, aY, 1, 1, 1);   // stages + prefetches tile 63
  QT(63, 65536, 0,     aY, aX, 0, 0, 0);   // tail: no stage/gate/prefetch

#undef QT

  // ---- epilogue: cosine normalize; C/D layout row=(l>>4)*4+r, col=l&15 --
  const float* nx = norms;
  const float* ny = norms + N;
  const int row0 = tile_row * 256 + wr * 128 + sl * 4;
  const int col0 = tile_col * 256 + wc * 128 + li;
  float riy[8];
#pragma unroll
  for (int n = 0; n < 8; ++n) riy[n] = __builtin_amdgcn_rcpf(ny[col0 + n * 16]);
#pragma unroll
  for (int m = 0; m < 8; ++m) {
#pragma unroll
    for (int r = 0; r < 4; ++r) {
      const int row = row0 + m * 16 + r;
      const float rix = __builtin_amdgcn_rcpf(nx[row]);
#pragma unroll
      for (int n = 0; n < 8; ++n) {
        const int col = col0 + n * 16;
        out[(size_t)row * N + col] = acc[m][n][r] * rix * riy[n];
      }
    }
  }
}

extern "C" void kernel_launch(void* const* d_in, const int* in_sizes, int n_in,
                              void* d_out, int out_size, void* d_ws, size_t ws_size,
                              hipStream_t stream) {
  const float* Z = (const float*)d_in[0];
  const float* Y = (const float*)d_in[1];
  float* out = (float*)d_out;

  ushort_t* Zb = (ushort_t*)d_ws;
  ushort_t* Yb = Zb + (size_t)N * N;
  float* norms = (float*)(Yb + (size_t)N * N);

  prep_kernel<<<2 * N, 256, 0, stream>>>(Z, Y, Zb, Yb, norms);
  gemm_kernel<<<(N / 256) * (N / 256), 256, 0, stream>>>(Zb, Yb, norms, out);
}

// Round 7
// 152.837 us; speedup vs baseline: 1.7720x; 1.7720x over previous
//
#include <hip/hip_runtime.h>

typedef __attribute__((ext_vector_type(8))) short bf16x8;
typedef __attribute__((ext_vector_type(4))) float f32x4;
typedef unsigned short ushort_t;

#define N 4096

__device__ __forceinline__ unsigned short f2bf_rne(float f) {
  unsigned int u = __float_as_uint(f);
  u += 0x7fffu + ((u >> 16) & 1u);   // round-to-nearest-even
  return (unsigned short)(u >> 16);
}

// One block per row (8192 rows: Z then Y). fp32 row norm + bf16 copy.
__global__ __launch_bounds__(256) void prep_kernel(
    const float* __restrict__ Z, const float* __restrict__ Y,
    ushort_t* __restrict__ Zb, ushort_t* __restrict__ Yb,
    float* __restrict__ norms) {
  const int r = blockIdx.x;
  const bool isZ = (r < N);
  const int rr = isZ ? r : r - N;
  const float* __restrict__ src = (isZ ? Z : Y) + (size_t)rr * N;
  ushort_t* __restrict__ dst = (isZ ? Zb : Yb) + (size_t)rr * N;
  const int t = threadIdx.x;

  float s = 0.f;
#pragma unroll
  for (int j = 0; j < 4; ++j) {
    const float4 v = ((const float4*)src)[j * 256 + t];
    s += v.x * v.x + v.y * v.y + v.z * v.z + v.w * v.w;
    short4 o;
    o.x = (short)f2bf_rne(v.x);
    o.y = (short)f2bf_rne(v.y);
    o.z = (short)f2bf_rne(v.z);
    o.w = (short)f2bf_rne(v.w);
    ((short4*)dst)[j * 256 + t] = o;
  }
#pragma unroll
  for (int off = 32; off > 0; off >>= 1) s += __shfl_down(s, off, 64);
  __shared__ float red[4];
  const int lane = t & 63, w = t >> 6;
  if (lane == 0) red[w] = s;
  __syncthreads();
  if (t == 0) norms[r] = sqrtf(red[0] + red[1] + red[2] + red[3]);
}

template <int VM>
__device__ __forceinline__ void vm_wait() {
  if constexpr (VM == 8) asm volatile("s_waitcnt vmcnt(8)" ::: "memory");
  else if constexpr (VM == 4) asm volatile("s_waitcnt vmcnt(4)" ::: "memory");
  else if constexpr (VM == 0) asm volatile("s_waitcnt vmcnt(0)" ::: "memory");
}

// 256x256 tile, BK=32, 8 waves (2M x 4N), 4-deep LDS ring, 1 barrier/tile.
// Tile body: 4 pinned groups of {3 ds_read (frags T+1) ; 8 MFMA (frags T)}
// so LDS reads execute under the MFMA pipe interval. Stage T+3 in group 0.
__global__ __launch_bounds__(512, 2) void gemm_kernel(
    const ushort_t* __restrict__ A,   // Zb [N][N]
    const ushort_t* __restrict__ B,   // Yb [N][N]
    const float* __restrict__ norms,  // [2N]: nx then ny
    float* __restrict__ out) {
  __shared__ __align__(16) char smem[131072];  // 4 bufs x (A 16K + B 16K)

  const int bid = blockIdx.x;                 // 256 blocks; bijective swizzle
  const int swz = (bid & 7) * 32 + (bid >> 3);
  const int tile_row = swz >> 4;
  const int tile_col = swz & 15;

  const int tid = threadIdx.x;
  const int l = tid & 63;
  const int w = tid >> 6;
  const int wr = w >> 2;      // M half
  const int wc = w & 3;       // N quarter
  const int li = l & 15;
  const int sl = l >> 4;

  // staging: chunk = q*512 + tid writes LDS bytes [chunk*16,+16) linearly;
  // LDS(row,slot) holds global(row, slot ^ ((row>>1)&3))  [involution]
  const ushort_t* pgA[2];
  const ushort_t* pgB[2];
#pragma unroll
  for (int q = 0; q < 2; ++q) {
    const int ch = q * 512 + tid;
    const int row = ch >> 2, slot = ch & 3;
    const int ss = slot ^ ((row >> 1) & 3);
    pgA[q] = A + (size_t)(tile_row * 256 + row) * N + ss * 8;
    pgB[q] = B + (size_t)(tile_col * 256 + row) * N + ss * 8;
  }

  auto stageA = [&](int t, int buf) {
#pragma unroll
    for (int q = 0; q < 2; ++q)
      __builtin_amdgcn_global_load_lds(
          (__attribute__((address_space(1))) void*)(pgA[q] + t * 32),
          (__attribute__((address_space(3))) void*)(smem + buf * 32768 +
                                                    q * 8192 + w * 1024),
          16, 0, 0);
  };
  auto stageB = [&](int t, int buf) {
#pragma unroll
    for (int q = 0; q < 2; ++q)
      __builtin_amdgcn_global_load_lds(
          (__attribute__((address_space(1))) void*)(pgB[q] + t * 32),
          (__attribute__((address_space(3))) void*)(smem + buf * 32768 + 16384 +
                                                    q * 8192 + w * 1024),
          16, 0, 0);
  };

  // fragment LDS byte offsets: lane reads row base+li, 16B slot sl,
  // swizzled slot = sl ^ ((li>>1)&3)
  const int ssl = sl ^ ((li >> 1) & 3);
  int offA[8], offB[4];
#pragma unroll
  for (int m = 0; m < 8; ++m)
    offA[m] = ((wr * 128 + m * 16 + li) * 32 + ssl * 8) * 2;
#pragma unroll
  for (int n = 0; n < 4; ++n)
    offB[n] = ((wc * 64 + n * 16 + li) * 32 + ssl * 8) * 2;

  f32x4 acc[8][4];
#pragma unroll
  for (int m = 0; m < 8; ++m)
#pragma unroll
    for (int n = 0; n < 4; ++n) acc[m][n] = (f32x4){0.f, 0.f, 0.f, 0.f};

  bf16x8 aF0[8], bF0[4], aF1[8], bF1[4];

#define SB __builtin_amdgcn_sched_barrier(0);

  // 8 MFMA on rows M0,M0+1 x all n, current frag set
#define MF2(AC, BC, M0) {                                                     \
    __builtin_amdgcn_s_setprio(1);                                            \
    _Pragma("unroll") for (int mm = 0; mm < 2; ++mm)                          \
    _Pragma("unroll") for (int n = 0; n < 4; ++n)                             \
      acc[(M0)+mm][n] = __builtin_amdgcn_mfma_f32_16x16x32_bf16(              \
          AC[(M0)+mm], BC[n], acc[(M0)+mm][n], 0, 0, 0);                      \
    __builtin_amdgcn_s_setprio(0); }

  // prologue: stage tiles 0,1,2; vmcnt(4) -> bufs 0,1 resident; prime F0
  stageA(0, 0); stageB(0, 0);
  stageA(1, 1); stageB(1, 1);
  stageA(2, 2); stageB(2, 2);
  vm_wait<4>();
  __builtin_amdgcn_s_barrier();
  SB;
#pragma unroll
  for (int m = 0; m < 8; ++m) aF0[m] = *(const bf16x8*)(smem + offA[m]);
#pragma unroll
  for (int n = 0; n < 4; ++n) bF0[n] = *(const bf16x8*)(smem + 16384 + offB[n]);

  // tile body: interleaved {reads(T+1) | MFMA(T)} groups, stage T+3 in G0
#define TB(T_, AC, BC, AN, BN, BUFN, DOSTAGE, VM, DOBAR)                      \
  {                                                                           \
    const char* pA_ = smem + (BUFN) * 32768;                                  \
    const char* pB_ = pA_ + 16384;                                            \
    /* G0: stage + B-reads 0..2, MFMA m0-1 */                                 \
    if (DOSTAGE) {                                                            \
      stageA((T_) + 3, ((T_) + 3) & 3);                                       \
      stageB((T_) + 3, ((T_) + 3) & 3);                                       \
    }                                                                         \
    BN[0] = *(const bf16x8*)(pB_ + offB[0]);                                  \
    BN[1] = *(const bf16x8*)(pB_ + offB[1]);                                  \
    BN[2] = *(const bf16x8*)(pB_ + offB[2]);                                  \
    SB; MF2(AC, BC, 0); SB;                                                   \
    /* G1 */                                                                  \
    BN[3] = *(const bf16x8*)(pB_ + offB[3]);                                  \
    AN[0] = *(const bf16x8*)(pA_ + offA[0]);                                  \
    AN[1] = *(const bf16x8*)(pA_ + offA[1]);                                  \
    SB; MF2(AC, BC, 2); SB;                                                   \
    /* G2 */                                                                  \
    AN[2] = *(const bf16x8*)(pA_ + offA[2]);                                  \
    AN[3] = *(const bf16x8*)(pA_ + offA[3]);                                  \
    AN[4] = *(const bf16x8*)(pA_ + offA[4]);                                  \
    SB; MF2(AC, BC, 4); SB;                                                   \
    /* G3 */                                                                  \
    AN[5] = *(const bf16x8*)(pA_ + offA[5]);                                  \
    AN[6] = *(const bf16x8*)(pA_ + offA[6]);                                  \
    AN[7] = *(const bf16x8*)(pA_ + offA[7]);                                  \
    SB; MF2(AC, BC, 6); SB;                                                   \
    vm_wait<VM>();                                                            \
    if (DOBAR) {                                                              \
      __builtin_amdgcn_s_barrier();                                           \
      SB;                                                                     \
    }                                                                         \
  }

  for (int t = 0; t < 124; t += 4) {
    TB(t + 0, aF0, bF0, aF1, bF1, 1, true, 4, true);
    TB(t + 1, aF1, bF1, aF0, bF0, 2, true, 4, true);
    TB(t + 2, aF0, bF0, aF1, bF1, 3, true, 4, true);
    TB(t + 3, aF1, bF1, aF0, bF0, 0, true, 4, true);
  }
  TB(124, aF0, bF0, aF1, bF1, 1, true, 4, true);    // stages tile 127
  TB(125, aF1, bF1, aF0, bF0, 2, false, 0, true);   // -> 127 resident
  TB(126, aF0, bF0, aF1, bF1, 3, false, -1, false); // last prefetch
#undef TB

  // final tile 127: MFMA only
  __builtin_amdgcn_s_setprio(1);
#pragma unroll
  for (int m = 0; m < 8; ++m)
#pragma unroll
    for (int n = 0; n < 4; ++n)
      acc[m][n] = __builtin_amdgcn_mfma_f32_16x16x32_bf16(aF1[m], bF1[n],
                                                          acc[m][n], 0, 0, 0);
  __builtin_amdgcn_s_setprio(0);

  // epilogue: cosine normalize; C/D layout row=(l>>4)*4+r, col=l&15
  const float* nx = norms;
  const float* ny = norms + N;
  const int row0 = tile_row * 256 + wr * 128 + sl * 4;
  const int col0 = tile_col * 256 + wc * 64 + li;
#pragma unroll
  for (int m = 0; m < 8; ++m) {
#pragma unroll
    for (int r = 0; r < 4; ++r) {
      const int row = row0 + m * 16 + r;
      const float nxr = nx[row];
#pragma unroll
      for (int n = 0; n < 4; ++n) {
        const int col = col0 + n * 16;
        const float denom = fmaxf(nxr * ny[col], 1e-8f);
        out[(size_t)row * N + col] = acc[m][n][r] / denom;
      }
    }
  }
}

extern "C" void kernel_launch(void* const* d_in, const int* in_sizes, int n_in,
                              void* d_out, int out_size, void* d_ws, size_t ws_size,
                              hipStream_t stream) {
  const float* Z = (const float*)d_in[0];
  const float* Y = (const float*)d_in[1];
  float* out = (float*)d_out;

  ushort_t* Zb = (ushort_t*)d_ws;
  ushort_t* Yb = Zb + (size_t)N * N;
  float* norms = (float*)(Yb + (size_t)N * N);

  prep_kernel<<<2 * N, 256, 0, stream>>>(Z, Y, Zb, Yb, norms);
  gemm_kernel<<<(N / 256) * (N / 256), 512, 0, stream>>>(Zb, Yb, norms, out);
}